// Round 2
// baseline (72602.722 us; speedup 1.0000x reference)
//
#include <hip/hip_runtime.h>
#include <math.h>

#define BDIM 128
#define TDIM 512
#define BT (BDIM*TDIM)

// ---------------------------------------------------------------------------
// Activation helpers (match jax.nn semantics)
// ---------------------------------------------------------------------------
__device__ __forceinline__ float eluf(float v){ return v > 0.f ? v : expm1f(v); }
__device__ __forceinline__ float softplusf(float v){ return fmaxf(v,0.f) + log1pf(expf(-fabsf(v))); }
__device__ __forceinline__ float sigmoidf(float v){ return 1.f/(1.f+expf(-v)); }

// ---------------------------------------------------------------------------
// Generic tiled GEMM (pre/post passes):  C[M,N] = epi( X[M,K] @ W_T[K,N] + bias )
// ---------------------------------------------------------------------------
struct GemmP {
  const float* x1; long ldx1;
  const float* x2; long ldx2;
  int split;
  const float* w; int ldw;
  const float* bias;      // n-dim output bias
  float* out;  long ldo;
  float* out2;            // PSCALE second output
  int M, N, K, k0;
};

enum { SRC_CONCAT=0 };
enum { EPI_ELU=0, EPI_PLAIN=1, EPI_PSCALE=3, EPI_ELU_T=4 };

template<int SRC, int EPI, int BM>
__global__ __launch_bounds__(256) void gemm_k(GemmP p)
{
  constexpr int TM = BM/16;
  __shared__ float  Xs[BM][16];
  __shared__ float4 Ws4[16][16];
  const int tid = threadIdx.x;
  const int nt = tid & 15;
  const int mt = tid >> 4;
  const int n0 = blockIdx.x * 64;
  const int m0 = blockIdx.y * BM;

  float acc[TM][4];
  #pragma unroll
  for (int i=0;i<TM;i++){ acc[i][0]=0.f; acc[i][1]=0.f; acc[i][2]=0.f; acc[i][3]=0.f; }

  const int ktiles = p.K / 16;
  for (int kt=0; kt<ktiles; ++kt){
    const int kbase = p.k0 + kt*16;
    {
      const int nload4 = BM*16/4;
      if (tid < nload4){
        const int mi = tid >> 2;
        const int kk = (tid & 3) * 4;
        const int kabs = kbase + kk;
        float4 v;
        const float* src; long row; int k2;
        if (kabs < p.split){ src = p.x1; row = (long)(m0+mi)*p.ldx1; k2 = kabs; }
        else               { src = p.x2; row = (long)(m0+mi)*p.ldx2; k2 = kabs - p.split; }
        if (src) v = *(const float4*)(src + row + k2);
        else { v.x=0.f; v.y=0.f; v.z=0.f; v.w=0.f; }
        *(float4*)(&Xs[mi][kk]) = v;
      }
    }
    {
      const int kk = tid >> 4;
      const int n4 = (tid & 15) * 4;
      const int n = n0 + n4;
      const long base = (long)(kbase + kk) * p.ldw + n;
      float4 v;
      if (n + 3 < p.N) v = *(const float4*)(p.w + base);
      else {
        v.x = (n+0 < p.N) ? p.w[base+0] : 0.f;
        v.y = (n+1 < p.N) ? p.w[base+1] : 0.f;
        v.z = (n+2 < p.N) ? p.w[base+2] : 0.f;
        v.w = (n+3 < p.N) ? p.w[base+3] : 0.f;
      }
      Ws4[kk][tid & 15] = v;
    }
    __syncthreads();
    #pragma unroll
    for (int kk=0; kk<16; ++kk){
      const float4 w4 = Ws4[kk][nt];
      #pragma unroll
      for (int i=0;i<TM;i++){
        const float xv = Xs[mt*TM+i][kk];
        acc[i][0] = fmaf(xv, w4.x, acc[i][0]);
        acc[i][1] = fmaf(xv, w4.y, acc[i][1]);
        acc[i][2] = fmaf(xv, w4.z, acc[i][2]);
        acc[i][3] = fmaf(xv, w4.w, acc[i][3]);
      }
    }
    __syncthreads();
  }
  #pragma unroll
  for (int i=0;i<TM;i++){
    const int m = m0 + mt*TM + i;
    #pragma unroll
    for (int j=0;j<4;j++){
      const int n = n0 + nt*4 + j;
      if (n >= p.N) continue;
      float v = acc[i][j];
      if (EPI == EPI_ELU){
        p.out[(long)m*p.ldo + n] = eluf(v + p.bias[n]);
      } else if (EPI == EPI_PLAIN){
        p.out[(long)m*p.ldo + n] = v + p.bias[n];
      } else if (EPI == EPI_ELU_T){
        // write transposed: out[t][n][b], m = b*T + t
        p.out[((long)(m & (TDIM-1))*512 + n)*128 + (m >> 9)] = eluf(v + p.bias[n]);
      } else { // EPI_PSCALE
        v += p.bias[n];
        if (n < 64) p.out [(long)m*64 + n]      = v;
        else        p.out2[(long)m*64 + (n-64)] = softplusf(v) + 0.1f;
      }
    }
  }
}

// ---------------------------------------------------------------------------
// Transpose: dst[C][R] <- src[R][C]
// ---------------------------------------------------------------------------
__global__ void transpose_k(const float* __restrict__ src, float* __restrict__ dst, int R, int C){
  __shared__ float tile[32][33];
  const int c0 = blockIdx.x*32, r0 = blockIdx.y*32;
  const int tx = threadIdx.x, ty = threadIdx.y; // 32 x 8
  for (int i=ty; i<32; i+=8){
    const int r = r0+i, c = c0+tx;
    tile[i][tx] = (r<R && c<C) ? src[(long)r*C + c] : 0.f;
  }
  __syncthreads();
  for (int i=ty; i<32; i+=8){
    const int r = r0+tx, c = c0+i;
    if (r<R && c<C) dst[(long)c*R + r] = tile[tx][i];
  }
}

// ---------------------------------------------------------------------------
// Persistent cooperative scan kernel
// 256 blocks x 512 threads. Block owns 2 columns of each 512-wide phase.
// All activations live in [col][batch] transposed rings (r-coalesced).
// Weights read via lane-uniform indices -> scalar s_load path.
// ---------------------------------------------------------------------------
struct ScanArgs {
  const float* __restrict__ act;        // [B,T,16]
  const float* __restrict__ pri_enc_w;  // [512,80]
  const float* __restrict__ pri_enc_b;  // [512]
  const float* __restrict__ gru_wi;     // [1536,512]
  const float* __restrict__ gru_bi;     // [1536]
  const float* __restrict__ gru_wh;     // [1536,512]
  const float* __restrict__ gru_bh;     // [1536]
  const float* __restrict__ pos_enc_w;  // [512,1024]
  const float* __restrict__ pos_enc_b;  // [512]
  const float* __restrict__ pos_dec_w;  // [128,512]
  const float* __restrict__ pos_dec_b;  // [128]
  const float* __restrict__ emb_T;      // [T][512][128]
  const float* __restrict__ eps_T;      // [T][64][128]
  float* __restrict__ det_hist;         // [T][512][128]
  float* __restrict__ st_hist;          // [T][64][128]
  float* __restrict__ qsh_hist;         // [T][64][128]
  float* __restrict__ qsc_hist;         // [T][64][128]
  float* __restrict__ x_ring;           // [512][128]
  float* __restrict__ qx_ring;          // [512][128]
  float* __restrict__ det_ring;         // [2][512][128]
  float* __restrict__ st_ring;          // [2][64][128]
  unsigned* bar;                        // barrier state (zeroed)
};

__device__ __forceinline__ void gbar(unsigned* bar, int blk, unsigned phase){
  __syncthreads();
  if (threadIdx.x == 0){
    unsigned* grp  = bar + (blk & 7)*16;
    unsigned* root = bar + 8*16;
    unsigned* rel  = bar + 9*16;
    unsigned v = __hip_atomic_fetch_add(grp, 1u, __ATOMIC_ACQ_REL, __HIP_MEMORY_SCOPE_AGENT);
    if (v == phase*32u + 31u){
      unsigned r = __hip_atomic_fetch_add(root, 1u, __ATOMIC_ACQ_REL, __HIP_MEMORY_SCOPE_AGENT);
      if (r == phase*8u + 7u){
        __hip_atomic_store(rel, phase+1u, __ATOMIC_RELEASE, __HIP_MEMORY_SCOPE_AGENT);
      }
    }
    while (__hip_atomic_load(rel, __ATOMIC_RELAXED, __HIP_MEMORY_SCOPE_AGENT) <= phase){
      __builtin_amdgcn_s_sleep(2);
    }
  }
  __syncthreads();
  __builtin_amdgcn_fence(__ATOMIC_ACQUIRE, "agent");
}

__global__ __launch_bounds__(512, 1) void scan_k(ScanArgs a)
{
  __shared__ float4 red4[3*512];   // 24 KB reduction buffer, conflict-free layout
  const int blk = blockIdx.x;      // 0..255
  const int tid = threadIdx.x;
  const int r   = tid & 127;
  const int q   = tid >> 7;        // k-quarter 0..3
  const int n0  = blk * 2;
  unsigned phase = 0;

  for (int t = 0; t < TDIM; ++t){
    const float* st_prev  = a.st_ring  + ((t+1)&1)*64*128;
    const float* det_prev = a.det_ring + ((t+1)&1)*512*128;
    float*       det_cur  = a.det_ring + (t&1)*512*128;

    // ---------- P1: x = elu([stoch_prev, act_t] @ pri_enc_w^T + b) ----------
    if (tid < 256){
      const int c = tid >> 7;          // 0..1 (uniform per wave)
      const int rr = tid & 127;
      const int n = n0 + c;
      const float* wr = a.pri_enc_w + (long)n*80;
      float acc = a.pri_enc_b[n];
      #pragma unroll 8
      for (int k=0;k<64;k++) acc = fmaf(st_prev[k*128 + rr], wr[k], acc);
      const float* ar = a.act + ((long)rr*TDIM + t)*16;
      #pragma unroll
      for (int j=0;j<16;j++) acc = fmaf(ar[j], wr[64+j], acc);
      a.x_ring[n*128 + rr] = eluf(acc);
    }
    gbar(a.bar, blk, phase++);

    // ---------- P2: GRU (6 dots per det col) + gates -> det ----------
    {
      float acc[12];
      #pragma unroll
      for (int j=0;j<12;j++) acc[j]=0.f;
      const int kb = q*128;
      for (int k=kb; k<kb+128; k+=4){
        float xv[4], dv[4];
        #pragma unroll
        for (int u=0;u<4;u++){ xv[u] = a.x_ring[(k+u)*128 + r]; dv[u] = det_prev[(k+u)*128 + r]; }
        #pragma unroll
        for (int u=0;u<4;u++){
          const int kk = k+u;
          #pragma unroll
          for (int c=0;c<2;c++){
            acc[c*6+0] = fmaf(xv[u], a.gru_wi[(long)(     n0+c)*512 + kk], acc[c*6+0]);
            acc[c*6+1] = fmaf(xv[u], a.gru_wi[(long)( 512+n0+c)*512 + kk], acc[c*6+1]);
            acc[c*6+2] = fmaf(xv[u], a.gru_wi[(long)(1024+n0+c)*512 + kk], acc[c*6+2]);
            acc[c*6+3] = fmaf(dv[u], a.gru_wh[(long)(     n0+c)*512 + kk], acc[c*6+3]);
            acc[c*6+4] = fmaf(dv[u], a.gru_wh[(long)( 512+n0+c)*512 + kk], acc[c*6+4]);
            acc[c*6+5] = fmaf(dv[u], a.gru_wh[(long)(1024+n0+c)*512 + kk], acc[c*6+5]);
          }
        }
      }
      #pragma unroll
      for (int jg=0;jg<3;jg++)
        red4[jg*512 + q*128 + r] = make_float4(acc[jg*4+0],acc[jg*4+1],acc[jg*4+2],acc[jg*4+3]);
      __syncthreads();
      if (tid < 128){
        float s[12];
        #pragma unroll
        for (int j=0;j<12;j++) s[j]=0.f;
        #pragma unroll
        for (int jg=0;jg<3;jg++){
          #pragma unroll
          for (int qq=0;qq<4;qq++){
            float4 v = red4[jg*512 + qq*128 + tid];
            s[jg*4+0]+=v.x; s[jg*4+1]+=v.y; s[jg*4+2]+=v.z; s[jg*4+3]+=v.w;
          }
        }
        #pragma unroll
        for (int c=0;c<2;c++){
          const int n = n0 + c;
          const float ir = s[c*6+0] + a.gru_bi[n];
          const float iz = s[c*6+1] + a.gru_bi[512+n];
          const float ia = s[c*6+2] + a.gru_bi[1024+n];
          const float hr = s[c*6+3] + a.gru_bh[n];
          const float hz = s[c*6+4] + a.gru_bh[512+n];
          const float ha = s[c*6+5] + a.gru_bh[1024+n];
          const float rg = sigmoidf(ir+hr);
          const float z  = sigmoidf(iz+hz);
          const float nn = tanhf(ia + rg*ha);
          const float dp = det_prev[n*128 + tid];
          const float dv = (1.f - z)*nn + z*dp;
          det_cur[n*128 + tid] = dv;
          a.det_hist[((long)t*512 + n)*128 + tid] = dv;
        }
      }
    }
    gbar(a.bar, blk, phase++);

    // ---------- P4: qx = elu([det, emb] @ pos_enc_w^T + b) ----------
    {
      float a0=0.f, a1=0.f;
      if (q < 2){
        const int kb = q*256;
        for (int k=kb; k<kb+256; k+=4){
          #pragma unroll
          for (int u=0;u<4;u++){
            const float av = det_cur[(k+u)*128 + r];
            a0 = fmaf(av, a.pos_enc_w[(long)(n0  )*1024 + k+u], a0);
            a1 = fmaf(av, a.pos_enc_w[(long)(n0+1)*1024 + k+u], a1);
          }
        }
      } else {
        const int kb = (q-2)*256;
        const float* embt = a.emb_T + (long)t*512*128;
        for (int k=kb; k<kb+256; k+=4){
          #pragma unroll
          for (int u=0;u<4;u++){
            const float av = embt[(k+u)*128 + r];
            a0 = fmaf(av, a.pos_enc_w[(long)(n0  )*1024 + 512 + k+u], a0);
            a1 = fmaf(av, a.pos_enc_w[(long)(n0+1)*1024 + 512 + k+u], a1);
          }
        }
      }
      red4[q*128 + r] = make_float4(a0, a1, 0.f, 0.f);
      __syncthreads();
      if (tid < 128){
        float s0=0.f, s1=0.f;
        #pragma unroll
        for (int qq=0;qq<4;qq++){ float4 v = red4[qq*128 + tid]; s0+=v.x; s1+=v.y; }
        a.qx_ring[(n0  )*128 + tid] = eluf(s0 + a.pos_enc_b[n0  ]);
        a.qx_ring[(n0+1)*128 + tid] = eluf(s1 + a.pos_enc_b[n0+1]);
      }
    }
    gbar(a.bar, blk, phase++);

    // ---------- P5: q = qx @ pos_dec^T + b ; stoch = sh + softplus*eps ----------
    if (blk < 64){
      float a0=0.f, a1=0.f;
      const int kb = q*128;
      for (int k=kb; k<kb+128; k+=4){
        #pragma unroll
        for (int u=0;u<4;u++){
          const float qv = a.qx_ring[(k+u)*128 + r];
          a0 = fmaf(qv, a.pos_dec_w[(long)blk     *512 + k+u], a0);
          a1 = fmaf(qv, a.pos_dec_w[(long)(blk+64)*512 + k+u], a1);
        }
      }
      red4[q*128 + r] = make_float4(a0, a1, 0.f, 0.f);
      __syncthreads();
      if (tid < 128){
        float sh=0.f, raw=0.f;
        #pragma unroll
        for (int qq=0;qq<4;qq++){ float4 v = red4[qq*128 + tid]; sh+=v.x; raw+=v.y; }
        sh  += a.pos_dec_b[blk];
        raw += a.pos_dec_b[blk+64];
        const float sc = softplusf(raw) + 0.1f;
        const float e  = a.eps_T[((long)t*64 + blk)*128 + tid];
        const float st = sh + sc*e;
        const long ho = ((long)t*64 + blk)*128 + tid;
        a.st_ring[(t&1)*64*128 + blk*128 + tid] = st;
        a.st_hist[ho]  = st;
        a.qsh_hist[ho] = sh;
        a.qsc_hist[ho] = sc;
      }
    }
    gbar(a.bar, blk, phase++);
  }
}

// ---------------------------------------------------------------------------
extern "C" void kernel_launch(void* const* d_in, const int* in_sizes, int n_in,
                              void* d_out, int out_size, void* d_ws, size_t ws_size,
                              hipStream_t stream)
{
  const float* obs       = (const float*)d_in[0];
  const float* act       = (const float*)d_in[1];
  const float* eps       = (const float*)d_in[2];
  const float* enc_w     = (const float*)d_in[3];
  const float* enc_b     = (const float*)d_in[4];
  const float* dec_w     = (const float*)d_in[5];
  const float* dec_b     = (const float*)d_in[6];
  const float* pri_enc_w = (const float*)d_in[7];
  const float* pri_enc_b = (const float*)d_in[8];
  const float* gru_wi    = (const float*)d_in[9];
  const float* gru_bi    = (const float*)d_in[10];
  const float* gru_wh    = (const float*)d_in[11];
  const float* gru_bh    = (const float*)d_in[12];
  const float* pri_d1_w  = (const float*)d_in[13];
  const float* pri_d1_b  = (const float*)d_in[14];
  const float* pri_d2_w  = (const float*)d_in[15];
  const float* pri_d2_b  = (const float*)d_in[16];
  const float* pos_enc_w = (const float*)d_in[17];
  const float* pos_enc_b = (const float*)d_in[18];
  const float* pos_dec_w = (const float*)d_in[19];
  const float* pos_dec_b = (const float*)d_in[20];

  // ---- output sections (stochs, dets, outs, q_sh, q_sc, p_sh, p_sc)
  float* out     = (float*)d_out;
  float* o_stoch = out;
  float* o_det   = o_stoch + (long)BT*64;
  float* o_outs  = o_det   + (long)BT*512;
  float* o_qsh   = o_outs  + (long)BT*66;
  float* o_qsc   = o_qsh   + (long)BT*64;
  float* o_psh   = o_qsc   + (long)BT*64;
  float* o_psc   = o_psh   + (long)BT*64;

  // ---- workspace carve-up (~339 MB fp32)
  float* w = (float*)d_ws;
  float* emb_T    = w; w += (long)TDIM*512*128;   // also reused as px post-scan
  float* det_hist = w; w += (long)TDIM*512*128;
  float* st_hist  = w; w += (long)TDIM*64*128;
  float* qsh_hist = w; w += (long)TDIM*64*128;
  float* qsc_hist = w; w += (long)TDIM*64*128;
  float* eps_T    = w; w += (long)TDIM*64*128;
  float* x_ring   = w; w += 512*128;
  float* qx_ring  = w; w += 512*128;
  float* det_ring = w; w += 2*512*128;
  float* st_ring  = w; w += 2*64*128;
  float* enc_wT   = w; w += 64*512;
  float* pri_d1T  = w; w += 512*512;
  float* pri_d2T  = w; w += 512*128;
  float* dec_wT   = w; w += 576*66;
  unsigned* bar   = (unsigned*)w; w += 256;

  // ---- zero barrier + ring init slots (re-poisoned to 0xAA before every call)
  hipMemsetAsync(bar, 0, 256*sizeof(unsigned), stream);
  hipMemsetAsync(det_ring, 0, 2*512*128*sizeof(float), stream);
  hipMemsetAsync(st_ring, 0, 2*64*128*sizeof(float), stream);

  // ---- pre-pass: weight transposes for pre/post GEMMs
  {
    struct { const float* s; float* d; int R, C; } tps[4] = {
      {enc_w,    enc_wT,  512, 64  },
      {pri_d1_w, pri_d1T, 512, 512 },
      {pri_d2_w, pri_d2T, 128, 512 },
      {dec_w,    dec_wT,  66,  576 },
    };
    for (int i=0;i<4;i++){
      dim3 g((tps[i].C+31)/32, (tps[i].R+31)/32), b(32,8);
      hipLaunchKernelGGL(transpose_k, g, b, 0, stream, tps[i].s, tps[i].d, tps[i].R, tps[i].C);
    }
  }
  // eps -> eps_T [T*64][128]
  hipLaunchKernelGGL(transpose_k, dim3((TDIM*64+31)/32, (128+31)/32), dim3(32,8), 0, stream,
                     eps, eps_T, 128, TDIM*64);
  // emb_T = elu(obs @ enc_w^T + b), written transposed [T][512][128]
  {
    GemmP p{}; p.x1=obs; p.ldx1=64; p.split=64; p.w=enc_wT; p.ldw=512;
    p.bias=enc_b; p.out=emb_T; p.ldo=512; p.M=BT; p.N=512; p.K=64; p.k0=0;
    hipLaunchKernelGGL((gemm_k<SRC_CONCAT,EPI_ELU_T,64>), dim3(8,BT/64,1), dim3(256), 0, stream, p);
  }

  // ---- persistent cooperative scan
  {
    ScanArgs sa;
    sa.act = act; sa.pri_enc_w = pri_enc_w; sa.pri_enc_b = pri_enc_b;
    sa.gru_wi = gru_wi; sa.gru_bi = gru_bi; sa.gru_wh = gru_wh; sa.gru_bh = gru_bh;
    sa.pos_enc_w = pos_enc_w; sa.pos_enc_b = pos_enc_b;
    sa.pos_dec_w = pos_dec_w; sa.pos_dec_b = pos_dec_b;
    sa.emb_T = emb_T; sa.eps_T = eps_T;
    sa.det_hist = det_hist; sa.st_hist = st_hist;
    sa.qsh_hist = qsh_hist; sa.qsc_hist = qsc_hist;
    sa.x_ring = x_ring; sa.qx_ring = qx_ring;
    sa.det_ring = det_ring; sa.st_ring = st_ring; sa.bar = bar;
    void* kargs[] = { &sa };
    hipLaunchCooperativeKernel((const void*)scan_k, dim3(256), dim3(512), kargs, 0, stream);
  }

  // ---- post-pass: transpose histories into [B,T,*] outputs
  hipLaunchKernelGGL(transpose_k, dim3(4, (TDIM*512+31)/32), dim3(32,8), 0, stream,
                     det_hist, o_det, TDIM*512, 128);
  hipLaunchKernelGGL(transpose_k, dim3(4, (TDIM*64+31)/32), dim3(32,8), 0, stream,
                     st_hist, o_stoch, TDIM*64, 128);
  hipLaunchKernelGGL(transpose_k, dim3(4, (TDIM*64+31)/32), dim3(32,8), 0, stream,
                     qsh_hist, o_qsh, TDIM*64, 128);
  hipLaunchKernelGGL(transpose_k, dim3(4, (TDIM*64+31)/32), dim3(32,8), 0, stream,
                     qsc_hist, o_qsc, TDIM*64, 128);

  // ---- prior decode (parallel over B*T)
  float* px = emb_T;  // reuse
  {
    GemmP p{}; p.x1 = o_det; p.ldx1 = 512; p.split = 512;
    p.w = pri_d1T; p.ldw = 512; p.bias = pri_d1_b;
    p.out = px; p.ldo = 512; p.M = BT; p.N = 512; p.K = 512; p.k0 = 0;
    hipLaunchKernelGGL((gemm_k<SRC_CONCAT,EPI_ELU,64>), dim3(8,BT/64,1), dim3(256), 0, stream, p);
  }
  {
    GemmP p{}; p.x1 = px; p.ldx1 = 512; p.split = 512;
    p.w = pri_d2T; p.ldw = 128; p.bias = pri_d2_b;
    p.out = o_psh; p.out2 = o_psc; p.M = BT; p.N = 128; p.K = 512; p.k0 = 0;
    hipLaunchKernelGGL((gemm_k<SRC_CONCAT,EPI_PSCALE,64>), dim3(2,BT/64,1), dim3(256), 0, stream, p);
  }
  // ---- final decoder
  {
    GemmP p{}; p.x1 = o_stoch; p.ldx1 = 64; p.x2 = o_det; p.ldx2 = 512; p.split = 64;
    p.w = dec_wT; p.ldw = 66; p.bias = dec_b;
    p.out = o_outs; p.ldo = 66; p.M = BT; p.N = 66; p.K = 576; p.k0 = 0;
    hipLaunchKernelGGL((gemm_k<SRC_CONCAT,EPI_PLAIN,64>), dim3(2,BT/64,1), dim3(256), 0, stream, p);
  }
}